// Round 4
// baseline (189.225 us; speedup 1.0000x reference)
//
#include <hip/hip_runtime.h>
#include <hip/hip_bf16.h>

typedef __attribute__((ext_vector_type(8))) short short8;
typedef __attribute__((ext_vector_type(4))) float f32x4;
typedef __attribute__((ext_vector_type(2))) unsigned int uint2v;
typedef __attribute__((ext_vector_type(4))) unsigned int uint4v;
typedef unsigned short u16;

#define MFMA_BF16(a, b, c) __builtin_amdgcn_mfma_f32_16x16x32_bf16(a, b, c, 0, 0, 0)

#define T_SEQ 2048
#define DMODEL 1024
#define NHEADS 16
#define DHEAD 64
#define NEG_BIG (-30000.0f)
#define QSCALE 0.1803368801111f  // 0.125 * log2(e): softmax in exp2 domain
#define RESCALE_THR 8.0f         // defer-max threshold (exp2 domain): P <= 2^8

#if __has_builtin(__builtin_amdgcn_exp2f)
#define EXP2(x) __builtin_amdgcn_exp2f(x)
#else
#define EXP2(x) exp2f(x)
#endif

__device__ __forceinline__ unsigned bfr(unsigned u) {
  return (u + 0x7fffu + ((u >> 16) & 1u)) >> 16;
}
__device__ __forceinline__ uint4v ld8bf(const float* __restrict__ p) {
  const uint4v a = *(const uint4v*)p;
  const uint4v b = *(const uint4v*)(p + 4);
  uint4v r;
  r[0] = bfr(a[0]) | (bfr(a[1]) << 16);
  r[1] = bfr(a[2]) | (bfr(a[3]) << 16);
  r[2] = bfr(b[0]) | (bfr(b[1]) << 16);
  r[3] = bfr(b[2]) | (bfr(b[3]) << 16);
  return r;
}
__device__ __forceinline__ u16 f2bf(float f) {
  unsigned u = __float_as_uint(f);
  u += 0x7fffu + ((u >> 16) & 1u);
  return (u16)(u >> 16);
}
// async global->LDS DMA, 16B per lane; lds dest must be uniform-base + lane*16
__device__ __forceinline__ void gld16(const u16* g, u16* l) {
  __builtin_amdgcn_global_load_lds(
      (const __attribute__((address_space(1))) unsigned int*)g,
      (__attribute__((address_space(3))) unsigned int*)l, 16, 0, 0);
}

// ---------------------------------------------------------------- cvt fp32->bf16
__global__ __launch_bounds__(256) void cvt_all(
    const float* __restrict__ x, const float* __restrict__ wq,
    const float* __restrict__ wk, const float* __restrict__ wv,
    const float* __restrict__ wo, u16* __restrict__ xh, u16* __restrict__ wqh,
    u16* __restrict__ wkh, u16* __restrict__ wvh, u16* __restrict__ woh) {
  int bi = blockIdx.x;
  const float* s;
  u16* d;
  size_t base;
  if (bi < 2048) {
    s = x; d = xh; base = (size_t)bi * 2048;
  } else {
    int k = (bi - 2048) >> 9;
    int r = (bi - 2048) & 511;
    s = (k == 0) ? wq : (k == 1) ? wk : (k == 2) ? wv : wo;
    d = (k == 0) ? wqh : (k == 1) ? wkh : (k == 2) ? wvh : woh;
    base = (size_t)r * 2048;
  }
  size_t i = base + (size_t)threadIdx.x * 8;
  *(uint4v*)&d[i] = ld8bf(&s[i]);
}

// ---------------------------------------------------------------- QKV proj (bf16)
// grid (32,8,3): z=0 Q (pre-scaled by 0.125*log2e), z=1 K -> (b,h,t,d);
// z=2 V -> TRANSPOSED (b,h,d,t). Double-buffered global_load_lds staging:
// issue stage(k+1) BEFORE compute(k); single barrier/iter.
__global__ __launch_bounds__(256) void gemm_qkv(
    const u16* __restrict__ X, const u16* __restrict__ Wq,
    const u16* __restrict__ Wk, const u16* __restrict__ Wv,
    u16* __restrict__ Qo, u16* __restrict__ Ko, u16* __restrict__ Vo) {
  __shared__ __attribute__((aligned(16))) u16 As[2][128 * 32];
  __shared__ __attribute__((aligned(16))) u16 Bs[2][128 * 32];
  const int tid = threadIdx.x, lane = tid & 63, w = tid >> 6;
  const int wm = (w >> 1) * 64, wn = (w & 1) * 64;
  const int lrow = lane & 15;
  const int lk = (lane >> 4) << 3;
  const int lq = (lane >> 4) << 2;
  const int mBase = blockIdx.x * 128, nBase = blockIdx.y * 128;
  const u16* Bt = (blockIdx.z == 0) ? Wq : (blockIdx.z == 1) ? Wk : Wv;
  u16* D = (blockIdx.z == 0) ? Qo : (blockIdx.z == 1) ? Ko : Vo;
  const float scale = (blockIdx.z == 0) ? QSCALE : 1.0f;

  f32x4 acc[4][4];
#pragma unroll
  for (int mi = 0; mi < 4; mi++)
#pragma unroll
    for (int ni = 0; ni < 4; ni++) acc[mi][ni] = (f32x4)0.0f;

  auto stage = [&](int buf, int k0) {
#pragma unroll
    for (int i = 0; i < 2; i++) {
      int c = i * 256 + tid;
      int r = c >> 2, kk = (c & 3) << 3;
      gld16(&X[(size_t)(mBase + r) * 1024 + k0 + kk], &As[buf][c * 8]);
      gld16(&Bt[(size_t)(nBase + r) * 1024 + k0 + kk], &Bs[buf][c * 8]);
    }
  };

  stage(0, 0);
  __syncthreads();
  int cur = 0;
  for (int k0 = 0; k0 < 1024; k0 += 32) {
    if (k0 + 32 < 1024) stage(cur ^ 1, k0 + 32);
    short8 af[4], bf[4];
#pragma unroll
    for (int mi = 0; mi < 4; mi++)
      af[mi] = *(const short8*)&As[cur][(wm + mi * 16 + lrow) * 32 + lk];
#pragma unroll
    for (int ni = 0; ni < 4; ni++)
      bf[ni] = *(const short8*)&Bs[cur][(wn + ni * 16 + lrow) * 32 + lk];
#pragma unroll
    for (int mi = 0; mi < 4; mi++)
#pragma unroll
      for (int ni = 0; ni < 4; ni++)
        acc[mi][ni] = MFMA_BF16(af[mi], bf[ni], acc[mi][ni]);
    __syncthreads();  // drains vmcnt (next tile landed) + lgkm
    cur ^= 1;
  }
  const int vz = (blockIdx.z == 2);
#pragma unroll
  for (int mi = 0; mi < 4; mi++)
#pragma unroll
    for (int r = 0; r < 4; r++) {
      int m = mBase + wm + mi * 16 + lq + r;
      int b = m >> 11, t = m & 2047;
#pragma unroll
      for (int ni = 0; ni < 4; ni++) {
        int n = nBase + wn + ni * 16 + lrow;
        int h = n >> 6, dd = n & 63;
        size_t idx = vz ? (((size_t)((b * NHEADS + h) * DHEAD + dd)) * T_SEQ + t)
                        : ((((size_t)(b * NHEADS + h)) * T_SEQ + t) * DHEAD + dd);
        D[idx] = f2bf(acc[mi][ni][r] * scale);
      }
    }
}

// ---------------------------------------------------------------- attention
// KVBLK=128: halves iteration count (17 iters per snake-pair block, still
// perfectly balanced), halving barrier/P-roundtrip/loop fixed costs that R3
// proved dominant (FETCH -10x left duration unchanged -> latency-bound).
// LDS (81920 B = 160KB/2 exactly, 2 blocks/CU):
//   P  [0,8192) u16    : 64 rows x 128, granule(8-u16)-XOR swizzle by row&7
//   K  [8192+buf*8192) : 128 kv-rows x 64 d, XOR-swizzled, dbuf
//   V  [24576+buf*8192): 64 d-rows x 128 kv, XOR-swizzled, dbuf
// Q staged directly global->VGPR (2 loads/phase). XCD-clustered decode
// (proven: FETCH 123MB->12.4MB). Tail tile: uniform mask kv_local>diagoff.
__global__ __launch_bounds__(256) void attn_snake(
    const u16* __restrict__ Qg, const u16* __restrict__ Kg,
    const u16* __restrict__ Vtg, u16* __restrict__ Ob) {
  __shared__ __attribute__((aligned(16))) u16 smem[40960];  // 81920 B

  const int tid = threadIdx.x;
  const int w = tid >> 6, lane = tid & 63;
  const int lrow = lane & 15;
  const int quad = lane >> 4;
  const int lk = quad << 3;
  const int rsw = lrow & 7;           // read-side swizzle key
  const int q_local = w * 16 + lrow;  // this lane's q-row within the 64-tile

  // XCD-clustered decode: id&7 = XCD -> bh group of 4 (2MB K/V fits L2)
  const int id = blockIdx.x;                    // 0..511
  const int j = (id >> 3) & 15;                 // snake pair index
  const int bh = (id & 7) * 4 + ((id >> 7) & 3);
  const int b = bh >> 4, h = bh & 15;
  const u16* Qp = Qg + (size_t)bh * T_SEQ * DHEAD;
  const u16* Kp = Kg + (size_t)bh * T_SEQ * DHEAD;
  const u16* Vp = Vtg + (size_t)bh * DHEAD * T_SEQ;

  // stage one 128-kv tile of K (128x64) and V (64x128); 8 gld16/thread.
  // LDS dest linear; global src pre-swizzled (rule 21 both-sides XOR).
  auto stage_kv = [&](int buf, int kvb) {
#pragma unroll
    for (int i = 0; i < 4; i++) {
      int c = i * 256 + tid;
      int rk = c >> 3, gk = c & 7;   // K: 8 granules/row
      gld16(&Kp[(size_t)(kvb + rk) * DHEAD + ((gk ^ (rk & 7)) << 3)],
            &smem[8192 + buf * 8192 + c * 8]);
      int rv = c >> 4, gv = c & 15;  // V: 16 granules/row
      gld16(&Vp[(size_t)rv * T_SEQ + kvb + ((gv ^ (rv & 7)) << 3)],
            &smem[24576 + buf * 8192 + c * 8]);
    }
  };

#pragma unroll
  for (int p = 0; p < 2; p++) {
    const int qt = p ? (31 - j) : j;
    const int qb = qt * 64;
    const int ktd = qt >> 1;                     // tile containing the diagonal
    const int diagoff = ((qt & 1) << 6) + q_local;

    __syncthreads();  // prior phase's K/V readers done
    stage_kv(0, 0);   // KV tile 0 -> buf 0
    short8 qf[2];
#pragma unroll
    for (int ks = 0; ks < 2; ks++)
      qf[ks] =
          *(const short8*)&Qp[(size_t)(qb + q_local) * DHEAD + ks * 32 + lk];

    float mst = NEG_BIG, lst = 0.f;
    f32x4 oacc[4];
#pragma unroll
    for (int nd = 0; nd < 4; nd++) oacc[nd] = (f32x4)0.0f;
    __syncthreads();  // tile-0 DMA drained

    int cur = 0;
    for (int kt = 0; kt <= ktd; kt++) {
      if (kt < ktd) stage_kv(cur ^ 1, (kt + 1) * 128);
      const u16* Kc = &smem[8192 + cur * 8192];
      const u16* Vc = &smem[24576 + cur * 8192];

      // S^T: s[kvt] col=lane&15=q_local, row(quad*4+r)=kv within 16-block
      f32x4 s[8];
      __builtin_amdgcn_s_setprio(1);
#pragma unroll
      for (int kvt = 0; kvt < 8; kvt++) {
        f32x4 a = (f32x4)0.0f;
#pragma unroll
        for (int ks = 0; ks < 2; ks++) {
          short8 kf = *(const short8*)&Kc[(kvt * 16 + lrow) * 64 +
                                          ((((ks << 2) + quad) ^ rsw) << 3)];
          a = MFMA_BF16(kf, qf[ks], a);
        }
        s[kvt] = a;
      }
      __builtin_amdgcn_s_setprio(0);

      if (kt == ktd) {  // diagonal/causal mask, uniform form
#pragma unroll
        for (int kvt = 0; kvt < 8; kvt++)
#pragma unroll
          for (int r = 0; r < 4; r++)
            if (kvt * 16 + quad * 4 + r > diagoff) s[kvt][r] = NEG_BIG;
      }

      // online softmax, per-lane scalar stats; explicit trees (short chains)
      float mx = NEG_BIG;
#pragma unroll
      for (int kvt = 0; kvt < 8; kvt++)
        mx = fmaxf(mx, fmaxf(fmaxf(s[kvt][0], s[kvt][1]),
                             fmaxf(s[kvt][2], s[kvt][3])));
      mx = fmaxf(mx, __shfl_xor(mx, 16));
      mx = fmaxf(mx, __shfl_xor(mx, 32));
      // T13 defer-max: skip O-rescale while max growth <= THR (P <= 2^8)
      if (!__all(mx <= mst + RESCALE_THR)) {
        float mn = fmaxf(mst, mx);
        float corr = EXP2(mst - mn);
        mst = mn;
        lst *= corr;
#pragma unroll
        for (int nd = 0; nd < 4; nd++) oacc[nd] *= corr;
      }
      float e[8];
#pragma unroll
      for (int kvt = 0; kvt < 8; kvt++) {
        f32x4 pv;
        pv[0] = EXP2(s[kvt][0] - mst);
        pv[1] = EXP2(s[kvt][1] - mst);
        pv[2] = EXP2(s[kvt][2] - mst);
        pv[3] = EXP2(s[kvt][3] - mst);
        s[kvt] = pv;
        e[kvt] = (pv[0] + pv[1]) + (pv[2] + pv[3]);
      }
      float ls = ((e[0] + e[1]) + (e[2] + e[3])) + ((e[4] + e[5]) + (e[6] + e[7]));
      ls += __shfl_xor(ls, 16);
      ls += __shfl_xor(ls, 32);
      lst += ls;

      // P store: row q_local (wave-private), granule-XOR swizzle; b64 packed
      // bf16 truncation (P in [0, 2^8], rel err < 0.4%).
#pragma unroll
      for (int kvt = 0; kvt < 8; kvt++) {
        uint2v pk;
        pk[0] = (__float_as_uint(s[kvt][0]) >> 16) |
                (__float_as_uint(s[kvt][1]) & 0xffff0000u);
        pk[1] = (__float_as_uint(s[kvt][2]) >> 16) |
                (__float_as_uint(s[kvt][3]) & 0xffff0000u);
        *(uint2v*)&smem[q_local * 128 +
                        ((((kvt << 1) + (quad >> 1)) ^ rsw) << 3) +
                        ((quad & 1) << 2)] = pk;
      }

      // O^T += V^T P^T: mfma(vf, pf) -> col=q_local, row=d within 16-block
      __builtin_amdgcn_s_setprio(1);
#pragma unroll
      for (int ks = 0; ks < 4; ks++) {
        short8 pf = *(const short8*)&smem[q_local * 128 +
                                          ((((ks << 2) + quad) ^ rsw) << 3)];
#pragma unroll
        for (int nd = 0; nd < 4; nd++) {
          short8 vf = *(const short8*)&Vc[(nd * 16 + lrow) * 128 +
                                          ((((ks << 2) + quad) ^ rsw) << 3)];
          oacc[nd] = MFMA_BF16(vf, pf, oacc[nd]);
        }
      }
      __builtin_amdgcn_s_setprio(0);

      __syncthreads();  // next-tile DMA drained; this tile's readers done
      cur ^= 1;
    }

    // epilogue: lane owns q-row qb+q_local fully; d = nd*16 + quad*4 + r
    float inv = 1.f / lst;
    size_t rowbase = ((size_t)(b * T_SEQ + qb + q_local)) * DMODEL + h * DHEAD;
#pragma unroll
    for (int nd = 0; nd < 4; nd++) {
      uint2v pk;
      pk[0] = (unsigned)f2bf(oacc[nd][0] * inv) |
              ((unsigned)f2bf(oacc[nd][1] * inv) << 16);
      pk[1] = (unsigned)f2bf(oacc[nd][2] * inv) |
              ((unsigned)f2bf(oacc[nd][3] * inv) << 16);
      *(uint2v*)&Ob[rowbase + nd * 16 + quad * 4] = pk;
    }
  }
}

// ---------------------------------------------------------------- out proj (bf16)
// BN=64 -> grid (32,16)=512 blocks = 2 blocks/CU.
__global__ __launch_bounds__(256) void gemm_out_bf(const u16* __restrict__ O,
                                                   const u16* __restrict__ Wo,
                                                   float* __restrict__ Out) {
  __shared__ __attribute__((aligned(16))) u16 As[2][128 * 32];
  __shared__ __attribute__((aligned(16))) u16 Bs[2][64 * 32];
  const int tid = threadIdx.x, lane = tid & 63, w = tid >> 6;
  const int wm = (w >> 1) * 64, wn = (w & 1) * 32;
  const int lrow = lane & 15;
  const int lk = (lane >> 4) << 3;
  const int lq = (lane >> 4) << 2;
  const int mBase = blockIdx.x * 128, nBase = blockIdx.y * 64;

  f32x4 acc[4][2];
#pragma unroll
  for (int mi = 0; mi < 4; mi++)
#pragma unroll
    for (int ni = 0; ni < 2; ni++) acc[mi][ni] = (f32x4)0.0f;

  auto stage = [&](int buf, int k0) {
#pragma unroll
    for (int i = 0; i < 2; i++) {
      int c = i * 256 + tid;
      int r = c >> 2, kk = (c & 3) << 3;
      gld16(&O[(size_t)(mBase + r) * 1024 + k0 + kk], &As[buf][c * 8]);
    }
    int r = tid >> 2, kk = (tid & 3) << 3;
    gld16(&Wo[(size_t)(nBase + r) * 1024 + k0 + kk], &Bs[buf][tid * 8]);
  };

  stage(0, 0);
  __syncthreads();
  int cur = 0;
  for (int k0 = 0; k0 < 1024; k0 += 32) {
    if (k0 + 32 < 1024) stage(cur ^ 1, k0 + 32);
    short8 af[4], bf[2];
#pragma unroll
    for (int mi = 0; mi < 4; mi++)
      af[mi] = *(const short8*)&As[cur][(wm + mi * 16 + lrow) * 32 + lk];
#pragma unroll
    for (int ni = 0; ni < 2; ni++)
      bf[ni] = *(const short8*)&Bs[cur][(wn + ni * 16 + lrow) * 32 + lk];
#pragma unroll
    for (int mi = 0; mi < 4; mi++)
#pragma unroll
      for (int ni = 0; ni < 2; ni++)
        acc[mi][ni] = MFMA_BF16(af[mi], bf[ni], acc[mi][ni]);
    __syncthreads();
    cur ^= 1;
  }
#pragma unroll
  for (int mi = 0; mi < 4; mi++)
#pragma unroll
    for (int r = 0; r < 4; r++) {
      int m = mBase + wm + mi * 16 + lq + r;
#pragma unroll
      for (int ni = 0; ni < 2; ni++)
        Out[(size_t)m * DMODEL + nBase + wn + ni * 16 + lrow] = acc[mi][ni][r];
    }
}

// ---------------------------------------------------------------- launch
extern "C" void kernel_launch(void* const* d_in, const int* in_sizes, int n_in,
                              void* d_out, int out_size, void* d_ws,
                              size_t ws_size, hipStream_t stream) {
  const float* x = (const float*)d_in[0];
  const float* Wq = (const float*)d_in[1];
  const float* Wk = (const float*)d_in[2];
  const float* Wv = (const float*)d_in[3];
  const float* Wo = (const float*)d_in[4];
  float* out = (float*)d_out;

  u16* xh = (u16*)d_ws;      // 4M elems
  u16* wqh = xh + 4194304;   // 1M each
  u16* wkh = wqh + 1048576;
  u16* wvh = wkh + 1048576;
  u16* woh = wvh + 1048576;
  u16* Q = woh + 1048576;    // 4M each; V stored transposed (b,h,d,t)
  u16* K = Q + 4194304;
  u16* V = K + 4194304;
  u16* O = V + 4194304;      // total 48 MB

  cvt_all<<<dim3(4096), 256, 0, stream>>>(x, Wq, Wk, Wv, Wo, xh, wqh, wkh, wvh, woh);
  gemm_qkv<<<dim3(32, 8, 3), 256, 0, stream>>>(xh, wqh, wkh, wvh, Q, K, V);
  attn_snake<<<dim3(512), 256, 0, stream>>>(Q, K, V, O);
  gemm_out_bf<<<dim3(32, 16), 256, 0, stream>>>(O, woh, out);
}

// Round 6
// 178.201 us; speedup vs baseline: 1.0619x; 1.0619x over previous
//
#include <hip/hip_runtime.h>
#include <hip/hip_bf16.h>

typedef __attribute__((ext_vector_type(8))) short short8;
typedef __attribute__((ext_vector_type(4))) float f32x4;
typedef __attribute__((ext_vector_type(2))) unsigned int uint2v;
typedef __attribute__((ext_vector_type(4))) unsigned int uint4v;
typedef unsigned short u16;

#define MFMA_BF16(a, b, c) __builtin_amdgcn_mfma_f32_16x16x32_bf16(a, b, c, 0, 0, 0)

#define T_SEQ 2048
#define DMODEL 1024
#define NHEADS 16
#define DHEAD 64
#define NEG_BIG (-30000.0f)
#define QSCALE 0.1803368801111f  // 0.125 * log2(e): softmax in exp2 domain
#define RESCALE_THR 8.0f         // defer-max threshold (exp2 domain): P <= 2^8

#if __has_builtin(__builtin_amdgcn_exp2f)
#define EXP2(x) __builtin_amdgcn_exp2f(x)
#else
#define EXP2(x) exp2f(x)
#endif

__device__ __forceinline__ unsigned bfr(unsigned u) {
  return (u + 0x7fffu + ((u >> 16) & 1u)) >> 16;
}
__device__ __forceinline__ uint4v ld8bf(const float* __restrict__ p) {
  const uint4v a = *(const uint4v*)p;
  const uint4v b = *(const uint4v*)(p + 4);
  uint4v r;
  r[0] = bfr(a[0]) | (bfr(a[1]) << 16);
  r[1] = bfr(a[2]) | (bfr(a[3]) << 16);
  r[2] = bfr(b[0]) | (bfr(b[1]) << 16);
  r[3] = bfr(b[2]) | (bfr(b[3]) << 16);
  return r;
}
__device__ __forceinline__ u16 f2bf(float f) {
  unsigned u = __float_as_uint(f);
  u += 0x7fffu + ((u >> 16) & 1u);
  return (u16)(u >> 16);
}
// async global->LDS DMA, 16B per lane; lds dest must be uniform-base + lane*16
__device__ __forceinline__ void gld16(const u16* g, u16* l) {
  __builtin_amdgcn_global_load_lds(
      (const __attribute__((address_space(1))) unsigned int*)g,
      (__attribute__((address_space(3))) unsigned int*)l, 16, 0, 0);
}

// ---------------------------------------------------------------- cvt fp32->bf16
__global__ __launch_bounds__(256) void cvt_all(
    const float* __restrict__ x, const float* __restrict__ wq,
    const float* __restrict__ wk, const float* __restrict__ wv,
    const float* __restrict__ wo, u16* __restrict__ xh, u16* __restrict__ wqh,
    u16* __restrict__ wkh, u16* __restrict__ wvh, u16* __restrict__ woh) {
  int bi = blockIdx.x;
  const float* s;
  u16* d;
  size_t base;
  if (bi < 2048) {
    s = x; d = xh; base = (size_t)bi * 2048;
  } else {
    int k = (bi - 2048) >> 9;
    int r = (bi - 2048) & 511;
    s = (k == 0) ? wq : (k == 1) ? wk : (k == 2) ? wv : wo;
    d = (k == 0) ? wqh : (k == 1) ? wkh : (k == 2) ? wvh : woh;
    base = (size_t)r * 2048;
  }
  size_t i = base + (size_t)threadIdx.x * 8;
  *(uint4v*)&d[i] = ld8bf(&s[i]);
}

// ---------------------------------------------------------------- QKV proj (bf16)
// grid (32,8,3): z=0 Q (pre-scaled by 0.125*log2e), z=1 K -> (b,h,t,d);
// z=2 V -> TRANSPOSED (b,h,d,t). Double-buffered global_load_lds staging.
// V epilogue: per-wave 64x64 LDS transpose (XOR-swizzled, wave-private, no
// barrier) -> 128B-coalesced stores along t (was 64-lane x 2B scatter).
__global__ __launch_bounds__(256) void gemm_qkv(
    const u16* __restrict__ X, const u16* __restrict__ Wq,
    const u16* __restrict__ Wk, const u16* __restrict__ Wv,
    u16* __restrict__ Qo, u16* __restrict__ Ko, u16* __restrict__ Vo) {
  __shared__ __attribute__((aligned(16))) u16 sm[16384];  // A dbuf | B dbuf; reused as TT
  const int tid = threadIdx.x, lane = tid & 63, w = tid >> 6;
  const int wm = (w >> 1) * 64, wn = (w & 1) * 64;
  const int lrow = lane & 15;
  const int lk = (lane >> 4) << 3;
  const int lq = (lane >> 4) << 2;
  const int mBase = blockIdx.x * 128, nBase = blockIdx.y * 128;
  const u16* Bt = (blockIdx.z == 0) ? Wq : (blockIdx.z == 1) ? Wk : Wv;
  u16* D = (blockIdx.z == 0) ? Qo : (blockIdx.z == 1) ? Ko : Vo;
  const float scale = (blockIdx.z == 0) ? QSCALE : 1.0f;

  f32x4 acc[4][4];
#pragma unroll
  for (int mi = 0; mi < 4; mi++)
#pragma unroll
    for (int ni = 0; ni < 4; ni++) acc[mi][ni] = (f32x4)0.0f;

  auto stage = [&](int buf, int k0) {
#pragma unroll
    for (int i = 0; i < 2; i++) {
      int c = i * 256 + tid;
      int r = c >> 2, kk = (c & 3) << 3;
      gld16(&X[(size_t)(mBase + r) * 1024 + k0 + kk], &sm[buf * 4096 + c * 8]);
      gld16(&Bt[(size_t)(nBase + r) * 1024 + k0 + kk],
            &sm[8192 + buf * 4096 + c * 8]);
    }
  };

  stage(0, 0);
  __syncthreads();
  int cur = 0;
  for (int k0 = 0; k0 < 1024; k0 += 32) {
    if (k0 + 32 < 1024) stage(cur ^ 1, k0 + 32);
    short8 af[4], bf[4];
#pragma unroll
    for (int mi = 0; mi < 4; mi++)
      af[mi] = *(const short8*)&sm[cur * 4096 + (wm + mi * 16 + lrow) * 32 + lk];
#pragma unroll
    for (int ni = 0; ni < 4; ni++)
      bf[ni] =
          *(const short8*)&sm[8192 + cur * 4096 + (wn + ni * 16 + lrow) * 32 + lk];
#pragma unroll
    for (int mi = 0; mi < 4; mi++)
#pragma unroll
      for (int ni = 0; ni < 4; ni++)
        acc[mi][ni] = MFMA_BF16(af[mi], bf[ni], acc[mi][ni]);
    __syncthreads();  // drains vmcnt (next tile landed) + lgkm
    cur ^= 1;
  }

  if (blockIdx.z != 2) {
#pragma unroll
    for (int mi = 0; mi < 4; mi++)
#pragma unroll
      for (int r = 0; r < 4; r++) {
        int m = mBase + wm + mi * 16 + lq + r;
        int b = m >> 11, t = m & 2047;
#pragma unroll
        for (int ni = 0; ni < 4; ni++) {
          int n = nBase + wn + ni * 16 + lrow;
          int h = n >> 6, dd = n & 63;
          D[(((size_t)(b * NHEADS + h)) * T_SEQ + t) * DHEAD + dd] =
              f2bf(acc[mi][ni][r] * scale);
        }
      }
  } else {
    // V: per-wave 64x64 transpose in LDS (granule-XOR swizzle), then
    // coalesced stores: 8 lanes x 16B = 128B contiguous along t per d-row.
    u16* TT = &sm[w * 4096];  // wave-private -> no barrier needed
#pragma unroll
    for (int mi = 0; mi < 4; mi++)
#pragma unroll
      for (int r = 0; r < 4; r++) {
        int t_loc = mi * 16 + lq + r;
#pragma unroll
        for (int ni = 0; ni < 4; ni++) {
          int d_loc = ni * 16 + lrow;
          TT[d_loc * 64 + ((((t_loc >> 3) ^ (d_loc & 7)) << 3) | (t_loc & 7))] =
              f2bf(acc[mi][ni][r]);
        }
      }
    const int b = (mBase + wm) >> 11;
    const int t0 = (mBase + wm) & 2047;
#pragma unroll
    for (int it = 0; it < 8; it++) {
      int d_loc = it * 8 + (lane >> 3);
      int ch = lane & 7;
      short8 v = *(const short8*)&TT[d_loc * 64 + ((ch ^ (d_loc & 7)) << 3)];
      int n = nBase + wn + d_loc;
      int h = n >> 6, dd = n & 63;
      *(uint4v*)&D[(((size_t)((b * NHEADS + h) * DHEAD + dd)) * T_SEQ) + t0 +
                   ch * 8] = *(const uint4v*)&v;
    }
  }
}

// ---------------------------------------------------------------- attention
// Per-q-tile blocks: grid 1024, LDS 40960B exactly -> 4 blocks/CU = 16
// waves/CU (2x R4's occupancy; R3/R4 proved attn is stall-bound at 8 waves).
// Decode: id&7 = XCD (bh-clustered, proven FETCH 123MB->12.4MB); qt arranged
// so consecutive r and r+32 get complementary tiles -> every CU's 4 resident
// blocks sum to 66 tile-iters regardless of scheduler shift.
// LDS (u16 offsets): Q/P [0,4096) stride-64 granule-XOR swizzled;
// K dbuf [4096,12288); V dbuf [12288,20480). R3's verified inner loop.
__global__ __launch_bounds__(256) void attn_qt(
    const u16* __restrict__ Qg, const u16* __restrict__ Kg,
    const u16* __restrict__ Vtg, u16* __restrict__ Ob) {
  __shared__ __attribute__((aligned(16))) u16 smem[20480];  // 40960 B

  const int tid = threadIdx.x;
  const int w = tid >> 6, lane = tid & 63;
  const int lrow = lane & 15;
  const int quad = lane >> 4;
  const int lk = quad << 3;
  const int rsw = lrow & 7;           // swizzle key (= q_local&7)
  const int q_local = w * 16 + lrow;  // this lane's q-row within the 64-tile

  const int id = blockIdx.x;  // 0..1023
  const int xcd = id & 7;
  const int r0 = id >> 3;     // 0..127
  const int rr = r0 & 31;
  const int bsub = r0 >> 5;   // 0..3
  const int qt = (bsub & 1) ? rr : (31 - rr);
  const int bh = xcd * 4 + bsub;
  const int b = bh >> 4, h = bh & 15;
  const int qb = qt * 64;
  const u16* Qp = Qg + (size_t)bh * T_SEQ * DHEAD;
  const u16* Kp = Kg + (size_t)bh * T_SEQ * DHEAD;
  const u16* Vp = Vtg + (size_t)bh * DHEAD * T_SEQ;

  auto stage_kv = [&](int buf, int kvb) {
#pragma unroll
    for (int i = 0; i < 2; i++) {
      int c = i * 256 + tid;
      int r = c >> 3;
      int sw = ((c & 7) ^ (r & 7)) << 3;  // pre-swizzled global col slot
      gld16(&Kp[(size_t)(kvb + r) * DHEAD + sw], &smem[4096 + buf * 4096 + c * 8]);
      gld16(&Vp[(size_t)r * T_SEQ + kvb + sw], &smem[12288 + buf * 4096 + c * 8]);
    }
  };

  // stage Q (64x64, stride-64, granule-XOR swizzle; coalesced global reads)
#pragma unroll
  for (int i = 0; i < 2; i++) {
    int c = i * 256 + tid;
    int r = c >> 3, g = c & 7;
    *(uint4v*)&smem[r * 64 + ((g ^ (r & 7)) << 3)] =
        *(const uint4v*)&Qp[(size_t)(qb + r) * DHEAD + (g << 3)];
  }
  stage_kv(0, 0);
  __syncthreads();  // Q (cross-wave LDS) + KV tile 0 DMA drained

  short8 qf[2];
#pragma unroll
  for (int ks = 0; ks < 2; ks++)
    qf[ks] = *(const short8*)&smem[q_local * 64 + ((((ks << 2) + quad) ^ rsw) << 3)];

  float mst = NEG_BIG, lst = 0.f;
  f32x4 oacc[4];
#pragma unroll
  for (int nd = 0; nd < 4; nd++) oacc[nd] = (f32x4)0.0f;

  const int ntiles = qt + 1;
  int cur = 0;
  for (int kt = 0; kt < ntiles; kt++) {
    const u16* Kc = &smem[4096 + cur * 4096];
    const u16* Vc = &smem[12288 + cur * 4096];
    if (kt + 1 < ntiles) stage_kv(cur ^ 1, (kt + 1) * 64);

    // S^T: s[kvt] has col=lane&15=q_local, row(quad*4+r)=kv within tile
    f32x4 s[4];
    __builtin_amdgcn_s_setprio(1);
#pragma unroll
    for (int kvt = 0; kvt < 4; kvt++) {
      f32x4 a = (f32x4)0.0f;
#pragma unroll
      for (int ks = 0; ks < 2; ks++) {
        short8 kf = *(const short8*)&Kc[(kvt * 16 + lrow) * 64 +
                                        ((((ks << 2) + quad) ^ rsw) << 3)];
        a = MFMA_BF16(kf, qf[ks], a);
      }
      s[kvt] = a;
    }
    __builtin_amdgcn_s_setprio(0);

    if (kt == qt) {  // causal mask: only the diagonal tile needs it
#pragma unroll
      for (int kvt = 0; kvt < 4; kvt++)
#pragma unroll
        for (int r = 0; r < 4; r++)
          if (kvt * 16 + quad * 4 + r > q_local) s[kvt][r] = NEG_BIG;
    }

    // online softmax, per-lane scalar stats (one q-row per lane)
    float mx = NEG_BIG;
#pragma unroll
    for (int kvt = 0; kvt < 4; kvt++)
      mx = fmaxf(mx, fmaxf(fmaxf(s[kvt][0], s[kvt][1]),
                           fmaxf(s[kvt][2], s[kvt][3])));
    mx = fmaxf(mx, __shfl_xor(mx, 16));
    mx = fmaxf(mx, __shfl_xor(mx, 32));
    // T13 defer-max: skip O-rescale while max growth <= THR (P <= 2^8)
    if (!__all(mx <= mst + RESCALE_THR)) {
      float mn = fmaxf(mst, mx);
      float corr = EXP2(mst - mn);
      mst = mn;
      lst *= corr;
#pragma unroll
      for (int nd = 0; nd < 4; nd++) oacc[nd] *= corr;
    }
    float ls = 0.f;
#pragma unroll
    for (int kvt = 0; kvt < 4; kvt++)
#pragma unroll
      for (int r = 0; r < 4; r++) {
        float pv = EXP2(s[kvt][r] - mst);
        s[kvt][r] = pv;
        ls += pv;
      }
    ls += __shfl_xor(ls, 16);
    ls += __shfl_xor(ls, 32);
    lst += ls;

    // P store: row q_local (wave-private), granule-XOR swizzle, b64 packed.
    // bf16 truncation (P in [0,2^8], rel err < 0.4%).
#pragma unroll
    for (int kvt = 0; kvt < 4; kvt++) {
      uint2v pk;
      pk[0] = (__float_as_uint(s[kvt][0]) >> 16) |
              (__float_as_uint(s[kvt][1]) & 0xffff0000u);
      pk[1] = (__float_as_uint(s[kvt][2]) >> 16) |
              (__float_as_uint(s[kvt][3]) & 0xffff0000u);
      *(uint2v*)&smem[q_local * 64 +
                      ((((kvt << 1) | (quad >> 1)) ^ rsw) << 3) +
                      ((quad & 1) << 2)] = pk;
    }

    // O^T += V^T P^T: mfma(vf, pf) -> col=q_local, row=d within tile
    __builtin_amdgcn_s_setprio(1);
#pragma unroll
    for (int ks = 0; ks < 2; ks++) {
      short8 pf = *(const short8*)&smem[q_local * 64 +
                                        ((((ks << 2) + quad) ^ rsw) << 3)];
#pragma unroll
      for (int nd = 0; nd < 4; nd++) {
        short8 vf = *(const short8*)&Vc[(nd * 16 + lrow) * 64 +
                                        ((((ks << 2) + quad) ^ rsw) << 3)];
        oacc[nd] = MFMA_BF16(vf, pf, oacc[nd]);
      }
    }
    __builtin_amdgcn_s_setprio(0);

    __syncthreads();  // next-tile DMA drained; this tile's readers done
    cur ^= 1;
  }

  // epilogue: lane owns q-row qb+q_local fully; d = nd*16 + quad*4 + r
  float inv = 1.f / lst;
  size_t rowbase = ((size_t)(b * T_SEQ + qb + q_local)) * DMODEL + h * DHEAD;
#pragma unroll
  for (int nd = 0; nd < 4; nd++) {
    uint2v pk;
    pk[0] = (unsigned)f2bf(oacc[nd][0] * inv) |
            ((unsigned)f2bf(oacc[nd][1] * inv) << 16);
    pk[1] = (unsigned)f2bf(oacc[nd][2] * inv) |
            ((unsigned)f2bf(oacc[nd][3] * inv) << 16);
    *(uint2v*)&Ob[rowbase + nd * 16 + quad * 4] = pk;
  }
}

// ---------------------------------------------------------------- out proj (bf16)
// BN=64 -> grid (32,16)=512 blocks = 2 blocks/CU.
__global__ __launch_bounds__(256) void gemm_out_bf(const u16* __restrict__ O,
                                                   const u16* __restrict__ Wo,
                                                   float* __restrict__ Out) {
  __shared__ __attribute__((aligned(16))) u16 As[2][128 * 32];
  __shared__ __attribute__((aligned(16))) u16 Bs[2][64 * 32];
  const int tid = threadIdx.x, lane = tid & 63, w = tid >> 6;
  const int wm = (w >> 1) * 64, wn = (w & 1) * 32;
  const int lrow = lane & 15;
  const int lk = (lane >> 4) << 3;
  const int lq = (lane >> 4) << 2;
  const int mBase = blockIdx.x * 128, nBase = blockIdx.y * 64;

  f32x4 acc[4][2];
#pragma unroll
  for (int mi = 0; mi < 4; mi++)
#pragma unroll
    for (int ni = 0; ni < 2; ni++) acc[mi][ni] = (f32x4)0.0f;

  auto stage = [&](int buf, int k0) {
#pragma unroll
    for (int i = 0; i < 2; i++) {
      int c = i * 256 + tid;
      int r = c >> 2, kk = (c & 3) << 3;
      gld16(&O[(size_t)(mBase + r) * 1024 + k0 + kk], &As[buf][c * 8]);
    }
    int r = tid >> 2, kk = (tid & 3) << 3;
    gld16(&Wo[(size_t)(nBase + r) * 1024 + k0 + kk], &Bs[buf][tid * 8]);
  };

  stage(0, 0);
  __syncthreads();
  int cur = 0;
  for (int k0 = 0; k0 < 1024; k0 += 32) {
    if (k0 + 32 < 1024) stage(cur ^ 1, k0 + 32);
    short8 af[4], bf[2];
#pragma unroll
    for (int mi = 0; mi < 4; mi++)
      af[mi] = *(const short8*)&As[cur][(wm + mi * 16 + lrow) * 32 + lk];
#pragma unroll
    for (int ni = 0; ni < 2; ni++)
      bf[ni] = *(const short8*)&Bs[cur][(wn + ni * 16 + lrow) * 32 + lk];
#pragma unroll
    for (int mi = 0; mi < 4; mi++)
#pragma unroll
      for (int ni = 0; ni < 2; ni++)
        acc[mi][ni] = MFMA_BF16(af[mi], bf[ni], acc[mi][ni]);
    __syncthreads();
    cur ^= 1;
  }
#pragma unroll
  for (int mi = 0; mi < 4; mi++)
#pragma unroll
    for (int r = 0; r < 4; r++) {
      int m = mBase + wm + mi * 16 + lq + r;
#pragma unroll
      for (int ni = 0; ni < 2; ni++)
        Out[(size_t)m * DMODEL + nBase + wn + ni * 16 + lrow] = acc[mi][ni][r];
    }
}

// ---------------------------------------------------------------- launch
extern "C" void kernel_launch(void* const* d_in, const int* in_sizes, int n_in,
                              void* d_out, int out_size, void* d_ws,
                              size_t ws_size, hipStream_t stream) {
  const float* x = (const float*)d_in[0];
  const float* Wq = (const float*)d_in[1];
  const float* Wk = (const float*)d_in[2];
  const float* Wv = (const float*)d_in[3];
  const float* Wo = (const float*)d_in[4];
  float* out = (float*)d_out;

  u16* xh = (u16*)d_ws;      // 4M elems
  u16* wqh = xh + 4194304;   // 1M each
  u16* wkh = wqh + 1048576;
  u16* wvh = wkh + 1048576;
  u16* woh = wvh + 1048576;
  u16* Q = woh + 1048576;    // 4M each; V stored transposed (b,h,d,t)
  u16* K = Q + 4194304;
  u16* V = K + 4194304;
  u16* O = V + 4194304;      // total 48 MB

  cvt_all<<<dim3(4096), 256, 0, stream>>>(x, Wq, Wk, Wv, Wo, xh, wqh, wkh, wvh, woh);
  gemm_qkv<<<dim3(32, 8, 3), 256, 0, stream>>>(xh, wqh, wkh, wvh, Q, K, V);
  attn_qt<<<dim3(1024), 256, 0, stream>>>(Q, K, V, O);
  gemm_out_bf<<<dim3(32, 16), 256, 0, stream>>>(O, woh, out);
}

// Round 7
// 175.149 us; speedup vs baseline: 1.0804x; 1.0174x over previous
//
#include <hip/hip_runtime.h>
#include <hip/hip_bf16.h>

typedef __attribute__((ext_vector_type(8))) short short8;
typedef __attribute__((ext_vector_type(4))) float f32x4;
typedef __attribute__((ext_vector_type(2))) unsigned int uint2v;
typedef __attribute__((ext_vector_type(4))) unsigned int uint4v;
typedef unsigned short u16;

#define MFMA_BF16(a, b, c) __builtin_amdgcn_mfma_f32_16x16x32_bf16(a, b, c, 0, 0, 0)

#define T_SEQ 2048
#define DMODEL 1024
#define NHEADS 16
#define DHEAD 64
#define NEG_BIG (-30000.0f)
#define QSCALE 0.1803368801111f  // 0.125 * log2(e): softmax in exp2 domain
#define RESCALE_THR 8.0f         // defer-max threshold (exp2 domain): P <= 2^8

#if __has_builtin(__builtin_amdgcn_exp2f)
#define EXP2(x) __builtin_amdgcn_exp2f(x)
#else
#define EXP2(x) exp2f(x)
#endif

__device__ __forceinline__ unsigned bfr(unsigned u) {
  return (u + 0x7fffu + ((u >> 16) & 1u)) >> 16;
}
__device__ __forceinline__ uint4v ld8bf(const float* __restrict__ p) {
  const uint4v a = *(const uint4v*)p;
  const uint4v b = *(const uint4v*)(p + 4);
  uint4v r;
  r[0] = bfr(a[0]) | (bfr(a[1]) << 16);
  r[1] = bfr(a[2]) | (bfr(a[3]) << 16);
  r[2] = bfr(b[0]) | (bfr(b[1]) << 16);
  r[3] = bfr(b[2]) | (bfr(b[3]) << 16);
  return r;
}
__device__ __forceinline__ u16 f2bf(float f) {
  unsigned u = __float_as_uint(f);
  u += 0x7fffu + ((u >> 16) & 1u);
  return (u16)(u >> 16);
}
// async global->LDS DMA, 16B per lane; lds dest must be uniform-base + lane*16
__device__ __forceinline__ void gld16(const u16* g, u16* l) {
  __builtin_amdgcn_global_load_lds(
      (const __attribute__((address_space(1))) unsigned int*)g,
      (__attribute__((address_space(3))) unsigned int*)l, 16, 0, 0);
}

// ---------------------------------------------------------------- cvt fp32->bf16
__global__ __launch_bounds__(256) void cvt_all(
    const float* __restrict__ x, const float* __restrict__ wq,
    const float* __restrict__ wk, const float* __restrict__ wv,
    const float* __restrict__ wo, u16* __restrict__ xh, u16* __restrict__ wqh,
    u16* __restrict__ wkh, u16* __restrict__ wvh, u16* __restrict__ woh) {
  int bi = blockIdx.x;
  const float* s;
  u16* d;
  size_t base;
  if (bi < 2048) {
    s = x; d = xh; base = (size_t)bi * 2048;
  } else {
    int k = (bi - 2048) >> 9;
    int r = (bi - 2048) & 511;
    s = (k == 0) ? wq : (k == 1) ? wk : (k == 2) ? wv : wo;
    d = (k == 0) ? wqh : (k == 1) ? wkh : (k == 2) ? wvh : woh;
    base = (size_t)r * 2048;
  }
  size_t i = base + (size_t)threadIdx.x * 8;
  *(uint4v*)&d[i] = ld8bf(&s[i]);
}

// ---------------------------------------------------------------- QKV proj (bf16)
// 1-D grid 768, XCD-swizzled: id&7 = XCD, x-chunk of 4 per XCD with x
// innermost -> A-panels (4 x 256KB = 1MB) stay L2-resident, B-panel shared by
// 4 consecutive blocks. Cuts panel re-fetch traffic ~5x (gemm was HBM-bound).
// z=0 Q (pre-scaled), z=1 K -> (b,h,t,d); z=2 V -> TRANSPOSED (b,h,d,t) via
// per-wave LDS transpose epilogue (128B-coalesced stores).
__global__ __launch_bounds__(256) void gemm_qkv(
    const u16* __restrict__ X, const u16* __restrict__ Wq,
    const u16* __restrict__ Wk, const u16* __restrict__ Wv,
    u16* __restrict__ Qo, u16* __restrict__ Ko, u16* __restrict__ Vo) {
  __shared__ __attribute__((aligned(16))) u16 sm[16384];  // A dbuf | B dbuf; reused as TT
  const int tid = threadIdx.x, lane = tid & 63, w = tid >> 6;
  const int wm = (w >> 1) * 64, wn = (w & 1) * 64;
  const int lrow = lane & 15;
  const int lk = (lane >> 4) << 3;
  const int lq = (lane >> 4) << 2;

  // XCD swizzle decode
  const int id = blockIdx.x;        // 0..767
  const int xcd = id & 7, r8 = id >> 3;   // r8: 0..95
  const int xo = r8 & 3, yz = r8 >> 2;    // yz: 0..23
  const int y = yz & 7, z = yz >> 3;      // y: 0..7, z: 0..2
  const int mBase = (xcd * 4 + xo) * 128, nBase = y * 128;

  const u16* Bt = (z == 0) ? Wq : (z == 1) ? Wk : Wv;
  u16* D = (z == 0) ? Qo : (z == 1) ? Ko : Vo;
  const float scale = (z == 0) ? QSCALE : 1.0f;

  f32x4 acc[4][4];
#pragma unroll
  for (int mi = 0; mi < 4; mi++)
#pragma unroll
    for (int ni = 0; ni < 4; ni++) acc[mi][ni] = (f32x4)0.0f;

  auto stage = [&](int buf, int k0) {
#pragma unroll
    for (int i = 0; i < 2; i++) {
      int c = i * 256 + tid;
      int r = c >> 2, kk = (c & 3) << 3;
      gld16(&X[(size_t)(mBase + r) * 1024 + k0 + kk], &sm[buf * 4096 + c * 8]);
      gld16(&Bt[(size_t)(nBase + r) * 1024 + k0 + kk],
            &sm[8192 + buf * 4096 + c * 8]);
    }
  };

  stage(0, 0);
  __syncthreads();
  int cur = 0;
  for (int k0 = 0; k0 < 1024; k0 += 32) {
    if (k0 + 32 < 1024) stage(cur ^ 1, k0 + 32);
    short8 af[4], bf[4];
#pragma unroll
    for (int mi = 0; mi < 4; mi++)
      af[mi] = *(const short8*)&sm[cur * 4096 + (wm + mi * 16 + lrow) * 32 + lk];
#pragma unroll
    for (int ni = 0; ni < 4; ni++)
      bf[ni] =
          *(const short8*)&sm[8192 + cur * 4096 + (wn + ni * 16 + lrow) * 32 + lk];
#pragma unroll
    for (int mi = 0; mi < 4; mi++)
#pragma unroll
      for (int ni = 0; ni < 4; ni++)
        acc[mi][ni] = MFMA_BF16(af[mi], bf[ni], acc[mi][ni]);
    __syncthreads();  // drains vmcnt (next tile landed) + lgkm
    cur ^= 1;
  }

  if (z != 2) {
#pragma unroll
    for (int mi = 0; mi < 4; mi++)
#pragma unroll
      for (int r = 0; r < 4; r++) {
        int m = mBase + wm + mi * 16 + lq + r;
        int b = m >> 11, t = m & 2047;
#pragma unroll
        for (int ni = 0; ni < 4; ni++) {
          int n = nBase + wn + ni * 16 + lrow;
          int h = n >> 6, dd = n & 63;
          D[(((size_t)(b * NHEADS + h)) * T_SEQ + t) * DHEAD + dd] =
              f2bf(acc[mi][ni][r] * scale);
        }
      }
  } else {
    // V: per-wave 64x64 transpose in LDS (granule-XOR swizzle), then
    // coalesced stores: 8 lanes x 16B = 128B contiguous along t per d-row.
    u16* TT = &sm[w * 4096];  // wave-private -> no barrier needed
#pragma unroll
    for (int mi = 0; mi < 4; mi++)
#pragma unroll
      for (int r = 0; r < 4; r++) {
        int t_loc = mi * 16 + lq + r;
#pragma unroll
        for (int ni = 0; ni < 4; ni++) {
          int d_loc = ni * 16 + lrow;
          TT[d_loc * 64 + ((((t_loc >> 3) ^ (d_loc & 7)) << 3) | (t_loc & 7))] =
              f2bf(acc[mi][ni][r]);
        }
      }
    const int b = (mBase + wm) >> 11;
    const int t0 = (mBase + wm) & 2047;
#pragma unroll
    for (int it = 0; it < 8; it++) {
      int d_loc = it * 8 + (lane >> 3);
      int ch = lane & 7;
      short8 v = *(const short8*)&TT[d_loc * 64 + ((ch ^ (d_loc & 7)) << 3)];
      int n = nBase + wn + d_loc;
      int h = n >> 6, dd = n & 63;
      *(uint4v*)&D[(((size_t)((b * NHEADS + h) * DHEAD + dd)) * T_SEQ) + t0 +
                   ch * 8] = *(const uint4v*)&v;
    }
  }
}

// ---------------------------------------------------------------- attention
// KV-SPLIT blocks: 512 thr = 2 wave-groups; group g handles kv tiles 2s+g
// concurrently with private (m,l,O), exact flash-merge at the end. Halves the
// critical path of the longest block (qt=31: 32 serial iters -> 16 super-
// iters), which R6 proved IS the attn duration (115k cy = 32 x 3593).
// Decode: qt DESCENDING so long blocks dispatch first (ids 0..511 = qt>=16);
// id&7 = XCD, 4 bh per XCD (proven FETCH 123->12.4MB). LDS 81920B = exactly
// 2 blocks/CU. Per-tile inner loop identical to R6 (verified).
// LDS map (u16): P[g] at g*4096, [0,8192); K slot(parity p, g) at
// 8192+(p*2+g)*4096; V same at 24576+...; merge reuses K area for O1 (f32)
// and V area for m1/l1.
__global__ __launch_bounds__(512) void attn_kvsplit(
    const u16* __restrict__ Qg, const u16* __restrict__ Kg,
    const u16* __restrict__ Vtg, u16* __restrict__ Ob) {
  __shared__ __attribute__((aligned(16))) u16 smem[40960];  // 81920 B

  const int tid = threadIdx.x;
  const int w = tid >> 6, lane = tid & 63;
  const int g = w >> 2;               // kv-parity group 0/1
  const int wg = w & 3;
  const int lrow = lane & 15;
  const int quad = lane >> 4;
  const int lk = quad << 3;
  const int rsw = lrow & 7;           // swizzle key
  const int q_local = wg * 16 + lrow;

  const int id = blockIdx.x;          // 0..1023
  const int xcd = id & 7;
  const int r0 = id >> 3;             // 0..127
  const int qt = 31 - (r0 >> 2);      // descending: longest blocks first
  const int bh = xcd * 4 + (r0 & 3);
  const int b = bh >> 4, h = bh & 15;
  const int qb = qt * 64;
  const u16* Qp = Qg + (size_t)bh * T_SEQ * DHEAD;
  const u16* Kp = Kg + (size_t)bh * T_SEQ * DHEAD;
  const u16* Vp = Vtg + (size_t)bh * DHEAD * T_SEQ;

  // stage tile T into slot (p, T&1); 512 thr x 16B = one 8KB tile per call
  auto stage_tile = [&](int T, int p) {
    if (T > qt) return;
    const int slot = (p << 1) | (T & 1);
    const int c = tid;          // 0..511
    const int r = c >> 3;       // row 0..63 (kv for K, d for V)
    const int sw = ((c & 7) ^ (r & 7)) << 3;  // pre-swizzled granule
    gld16(&Kp[(size_t)(T * 64 + r) * DHEAD + sw],
          &smem[8192 + slot * 4096 + c * 8]);
    gld16(&Vp[(size_t)r * T_SEQ + T * 64 + sw],
          &smem[24576 + slot * 4096 + c * 8]);
  };

  stage_tile(0, 0);
  stage_tile(1, 0);

  short8 qf[2];
#pragma unroll
  for (int ks = 0; ks < 2; ks++)
    qf[ks] = *(const short8*)&Qp[(size_t)(qb + q_local) * DHEAD + ks * 32 + lk];

  float mst = NEG_BIG, lst = 0.f;
  f32x4 oacc[4];
#pragma unroll
  for (int nd = 0; nd < 4; nd++) oacc[nd] = (f32x4)0.0f;
  __syncthreads();  // tile 0/1 DMA drained

  const int Smax = (qt + 2) >> 1;  // ceil((qt+1)/2)
  for (int s = 0; s < Smax; s++) {
    const int p = s & 1;
    stage_tile(2 * s + 2, p ^ 1);  // prefetch next super-iter's pair
    stage_tile(2 * s + 3, p ^ 1);
    const int myt = 2 * s + g;
    if (myt <= qt) {
      const u16* Kc = &smem[8192 + ((p << 1) | g) * 4096];
      const u16* Vc = &smem[24576 + ((p << 1) | g) * 4096];

      // S^T: s[kvt] has col=lane&15=q_local, row(quad*4+r)=kv within tile
      f32x4 sv[4];
      __builtin_amdgcn_s_setprio(1);
#pragma unroll
      for (int kvt = 0; kvt < 4; kvt++) {
        f32x4 a = (f32x4)0.0f;
#pragma unroll
        for (int ks = 0; ks < 2; ks++) {
          short8 kf = *(const short8*)&Kc[(kvt * 16 + lrow) * 64 +
                                          ((((ks << 2) + quad) ^ rsw) << 3)];
          a = MFMA_BF16(kf, qf[ks], a);
        }
        sv[kvt] = a;
      }
      __builtin_amdgcn_s_setprio(0);

      if (myt == qt) {  // causal mask on the diagonal tile
#pragma unroll
        for (int kvt = 0; kvt < 4; kvt++)
#pragma unroll
          for (int r = 0; r < 4; r++)
            if (kvt * 16 + quad * 4 + r > q_local) sv[kvt][r] = NEG_BIG;
      }

      // online softmax, per-lane scalar stats
      float mx = NEG_BIG;
#pragma unroll
      for (int kvt = 0; kvt < 4; kvt++)
        mx = fmaxf(mx, fmaxf(fmaxf(sv[kvt][0], sv[kvt][1]),
                             fmaxf(sv[kvt][2], sv[kvt][3])));
      mx = fmaxf(mx, __shfl_xor(mx, 16));
      mx = fmaxf(mx, __shfl_xor(mx, 32));
      if (!__all(mx <= mst + RESCALE_THR)) {  // T13 defer-max
        float mn = fmaxf(mst, mx);
        float corr = EXP2(mst - mn);
        mst = mn;
        lst *= corr;
#pragma unroll
        for (int nd = 0; nd < 4; nd++) oacc[nd] *= corr;
      }
      float ls = 0.f;
#pragma unroll
      for (int kvt = 0; kvt < 4; kvt++)
#pragma unroll
        for (int r = 0; r < 4; r++) {
          float pv = EXP2(sv[kvt][r] - mst);
          sv[kvt][r] = pv;
          ls += pv;
        }
      ls += __shfl_xor(ls, 16);
      ls += __shfl_xor(ls, 32);
      lst += ls;

      // P store (group-private region, wave-private rows, XOR swizzle)
#pragma unroll
      for (int kvt = 0; kvt < 4; kvt++) {
        uint2v pk;
        pk[0] = (__float_as_uint(sv[kvt][0]) >> 16) |
                (__float_as_uint(sv[kvt][1]) & 0xffff0000u);
        pk[1] = (__float_as_uint(sv[kvt][2]) >> 16) |
                (__float_as_uint(sv[kvt][3]) & 0xffff0000u);
        *(uint2v*)&smem[g * 4096 + q_local * 64 +
                        ((((kvt << 1) | (quad >> 1)) ^ rsw) << 3) +
                        ((quad & 1) << 2)] = pk;
      }

      // O^T += V^T P^T
      __builtin_amdgcn_s_setprio(1);
#pragma unroll
      for (int ks = 0; ks < 2; ks++) {
        short8 pf = *(const short8*)&smem[g * 4096 + q_local * 64 +
                                          ((((ks << 2) + quad) ^ rsw) << 3)];
#pragma unroll
        for (int nd = 0; nd < 4; nd++) {
          short8 vf = *(const short8*)&Vc[(nd * 16 + lrow) * 64 +
                                          ((((ks << 2) + quad) ^ rsw) << 3)];
          oacc[nd] = MFMA_BF16(vf, pf, oacc[nd]);
        }
      }
      __builtin_amdgcn_s_setprio(0);
    }
    __syncthreads();  // next pair's DMA drained; this pair's readers done
  }

  // ---- merge: group 1 publishes (O1,m1,l1); group 0 combines and writes.
  // K/V staging areas are free now. O1 f32 granule-XOR-swizzled (2-way max).
  float* O1 = (float*)&smem[8192];    // 64q x 64d f32 = 16 KB
  float* ml = (float*)&smem[24576];   // m1[64], l1[64]
  if (g == 1) {
#pragma unroll
    for (int nd = 0; nd < 4; nd++)
      *(f32x4*)&O1[q_local * 64 + ((((nd << 2) | quad) ^ rsw) << 2)] = oacc[nd];
    if (quad == 0) {
      ml[q_local] = mst;
      ml[64 + q_local] = lst;
    }
  }
  __syncthreads();
  if (g == 0) {
    const float m1 = ml[q_local], l1 = ml[64 + q_local];
    const float M = fmaxf(mst, m1);
    const float c0 = EXP2(mst - M), c1 = EXP2(m1 - M);
    const float inv = 1.f / (c0 * lst + c1 * l1);
    size_t rowbase = ((size_t)(b * T_SEQ + qb + q_local)) * DMODEL + h * DHEAD;
#pragma unroll
    for (int nd = 0; nd < 4; nd++) {
      f32x4 o1 = *(const f32x4*)&O1[q_local * 64 +
                                    ((((nd << 2) | quad) ^ rsw) << 2)];
      uint2v pk;
      pk[0] = (unsigned)f2bf((c0 * oacc[nd][0] + c1 * o1[0]) * inv) |
              ((unsigned)f2bf((c0 * oacc[nd][1] + c1 * o1[1]) * inv) << 16);
      pk[1] = (unsigned)f2bf((c0 * oacc[nd][2] + c1 * o1[2]) * inv) |
              ((unsigned)f2bf((c0 * oacc[nd][3] + c1 * o1[3]) * inv) << 16);
      *(uint2v*)&Ob[rowbase + nd * 16 + quad * 4] = pk;
    }
  }
}

// ---------------------------------------------------------------- out proj (bf16)
// 1-D grid 512, XCD-swizzled like gemm_qkv: x-chunk of 4 per XCD, x
// innermost. BN=64 -> 2 blocks/CU.
__global__ __launch_bounds__(256) void gemm_out_bf(const u16* __restrict__ O,
                                                   const u16* __restrict__ Wo,
                                                   float* __restrict__ Out) {
  __shared__ __attribute__((aligned(16))) u16 As[2][128 * 32];
  __shared__ __attribute__((aligned(16))) u16 Bs[2][64 * 32];
  const int tid = threadIdx.x, lane = tid & 63, w = tid >> 6;
  const int wm = (w >> 1) * 64, wn = (w & 1) * 32;
  const int lrow = lane & 15;
  const int lk = (lane >> 4) << 3;
  const int lq = (lane >> 4) << 2;

  const int id = blockIdx.x;            // 0..511
  const int xcd = id & 7, r8 = id >> 3; // 0..63
  const int xo = r8 & 3, y = r8 >> 2;   // y: 0..15
  const int mBase = (xcd * 4 + xo) * 128, nBase = y * 64;

  f32x4 acc[4][2];
#pragma unroll
  for (int mi = 0; mi < 4; mi++)
#pragma unroll
    for (int ni = 0; ni < 2; ni++) acc[mi][ni] = (f32x4)0.0f;

  auto stage = [&](int buf, int k0) {
#pragma unroll
    for (int i = 0; i < 2; i++) {
      int c = i * 256 + tid;
      int r = c >> 2, kk = (c & 3) << 3;
      gld16(&O[(size_t)(mBase + r) * 1024 + k0 + kk], &As[buf][c * 8]);
    }
    int r = tid >> 2, kk = (tid & 3) << 3;
    gld16(&Wo[(size_t)(nBase + r) * 1024 + k0 + kk], &Bs[buf][tid * 8]);
  };

  stage(0, 0);
  __syncthreads();
  int cur = 0;
  for (int k0 = 0; k0 < 1024; k0 += 32) {
    if (k0 + 32 < 1024) stage(cur ^ 1, k0 + 32);
    short8 af[4], bf[2];
#pragma unroll
    for (int mi = 0; mi < 4; mi++)
      af[mi] = *(const short8*)&As[cur][(wm + mi * 16 + lrow) * 32 + lk];
#pragma unroll
    for (int ni = 0; ni < 2; ni++)
      bf[ni] = *(const short8*)&Bs[cur][(wn + ni * 16 + lrow) * 32 + lk];
#pragma unroll
    for (int mi = 0; mi < 4; mi++)
#pragma unroll
      for (int ni = 0; ni < 2; ni++)
        acc[mi][ni] = MFMA_BF16(af[mi], bf[ni], acc[mi][ni]);
    __syncthreads();
    cur ^= 1;
  }
#pragma unroll
  for (int mi = 0; mi < 4; mi++)
#pragma unroll
    for (int r = 0; r < 4; r++) {
      int m = mBase + wm + mi * 16 + lq + r;
#pragma unroll
      for (int ni = 0; ni < 2; ni++)
        Out[(size_t)m * DMODEL + nBase + wn + ni * 16 + lrow] = acc[mi][ni][r];
    }
}

// ---------------------------------------------------------------- launch
extern "C" void kernel_launch(void* const* d_in, const int* in_sizes, int n_in,
                              void* d_out, int out_size, void* d_ws,
                              size_t ws_size, hipStream_t stream) {
  const float* x = (const float*)d_in[0];
  const float* Wq = (const float*)d_in[1];
  const float* Wk = (const float*)d_in[2];
  const float* Wv = (const float*)d_in[3];
  const float* Wo = (const float*)d_in[4];
  float* out = (float*)d_out;

  u16* xh = (u16*)d_ws;      // 4M elems
  u16* wqh = xh + 4194304;   // 1M each
  u16* wkh = wqh + 1048576;
  u16* wvh = wkh + 1048576;
  u16* woh = wvh + 1048576;
  u16* Q = woh + 1048576;    // 4M each; V stored transposed (b,h,d,t)
  u16* K = Q + 4194304;
  u16* V = K + 4194304;
  u16* O = V + 4194304;      // total 48 MB

  cvt_all<<<dim3(4096), 256, 0, stream>>>(x, Wq, Wk, Wv, Wo, xh, wqh, wkh, wvh, woh);
  gemm_qkv<<<dim3(768), 256, 0, stream>>>(xh, wqh, wkh, wvh, Q, K, V);
  attn_kvsplit<<<dim3(1024), 512, 0, stream>>>(Q, K, V, O);
  gemm_out_bf<<<dim3(512), 256, 0, stream>>>(O, woh, out);
}

// Round 8
// 171.084 us; speedup vs baseline: 1.1060x; 1.0238x over previous
//
#include <hip/hip_runtime.h>
#include <hip/hip_bf16.h>

typedef __attribute__((ext_vector_type(8))) short short8;
typedef __attribute__((ext_vector_type(4))) float f32x4;
typedef __attribute__((ext_vector_type(16))) float f32x16;
typedef __attribute__((ext_vector_type(2))) unsigned int uint2v;
typedef __attribute__((ext_vector_type(4))) unsigned int uint4v;
typedef unsigned short u16;

#define MFMA_BF16(a, b, c) __builtin_amdgcn_mfma_f32_16x16x32_bf16(a, b, c, 0, 0, 0)
#define MFMA32(a, b, c) __builtin_amdgcn_mfma_f32_32x32x16_bf16(a, b, c, 0, 0, 0)

#define T_SEQ 2048
#define DMODEL 1024
#define NHEADS 16
#define DHEAD 64
#define NEG_BIG (-30000.0f)
#define QSCALE 0.1803368801111f  // 0.125 * log2(e): softmax in exp2 domain
#define RESCALE_THR 8.0f         // defer-max threshold (exp2 domain): P <= 2^8

#if __has_builtin(__builtin_amdgcn_exp2f)
#define EXP2(x) __builtin_amdgcn_exp2f(x)
#else
#define EXP2(x) exp2f(x)
#endif

__device__ __forceinline__ unsigned bfr(unsigned u) {
  return (u + 0x7fffu + ((u >> 16) & 1u)) >> 16;
}
__device__ __forceinline__ uint4v ld8bf(const float* __restrict__ p) {
  const uint4v a = *(const uint4v*)p;
  const uint4v b = *(const uint4v*)(p + 4);
  uint4v r;
  r[0] = bfr(a[0]) | (bfr(a[1]) << 16);
  r[1] = bfr(a[2]) | (bfr(a[3]) << 16);
  r[2] = bfr(b[0]) | (bfr(b[1]) << 16);
  r[3] = bfr(b[2]) | (bfr(b[3]) << 16);
  return r;
}
__device__ __forceinline__ u16 f2bf(float f) {
  unsigned u = __float_as_uint(f);
  u += 0x7fffu + ((u >> 16) & 1u);
  return (u16)(u >> 16);
}
// packed bf16 truncation (P in [0,2^8], rel err < 0.4%)
__device__ __forceinline__ unsigned pk2(float a, float b) {
  return (__float_as_uint(a) >> 16) | (__float_as_uint(b) & 0xffff0000u);
}
// async global->LDS DMA, 16B per lane; lds dest must be uniform-base + lane*16
__device__ __forceinline__ void gld16(const u16* g, u16* l) {
  __builtin_amdgcn_global_load_lds(
      (const __attribute__((address_space(1))) unsigned int*)g,
      (__attribute__((address_space(3))) unsigned int*)l, 16, 0, 0);
}

// ---------------------------------------------------------------- cvt fp32->bf16
__global__ __launch_bounds__(256) void cvt_all(
    const float* __restrict__ x, const float* __restrict__ wq,
    const float* __restrict__ wk, const float* __restrict__ wv,
    const float* __restrict__ wo, u16* __restrict__ xh, u16* __restrict__ wqh,
    u16* __restrict__ wkh, u16* __restrict__ wvh, u16* __restrict__ woh) {
  int bi = blockIdx.x;
  const float* s;
  u16* d;
  size_t base;
  if (bi < 2048) {
    s = x; d = xh; base = (size_t)bi * 2048;
  } else {
    int k = (bi - 2048) >> 9;
    int r = (bi - 2048) & 511;
    s = (k == 0) ? wq : (k == 1) ? wk : (k == 2) ? wv : wo;
    d = (k == 0) ? wqh : (k == 1) ? wkh : (k == 2) ? wvh : woh;
    base = (size_t)r * 2048;
  }
  size_t i = base + (size_t)threadIdx.x * 8;
  *(uint4v*)&d[i] = ld8bf(&s[i]);
}

// ---------------------------------------------------------------- QKV proj (bf16)
// 1-D grid 768, XCD-swizzled (id&7 = XCD, x-chunk of 4 innermost). z=0 Q
// (pre-scaled), z=1 K -> (b,h,t,d); z=2 V -> TRANSPOSED (b,h,d,t) via
// per-wave LDS transpose epilogue (128B-coalesced stores).
__global__ __launch_bounds__(256) void gemm_qkv(
    const u16* __restrict__ X, const u16* __restrict__ Wq,
    const u16* __restrict__ Wk, const u16* __restrict__ Wv,
    u16* __restrict__ Qo, u16* __restrict__ Ko, u16* __restrict__ Vo) {
  __shared__ __attribute__((aligned(16))) u16 sm[16384];  // A dbuf | B dbuf; reused as TT
  const int tid = threadIdx.x, lane = tid & 63, w = tid >> 6;
  const int wm = (w >> 1) * 64, wn = (w & 1) * 64;
  const int lrow = lane & 15;
  const int lk = (lane >> 4) << 3;
  const int lq = (lane >> 4) << 2;

  const int id = blockIdx.x;        // 0..767
  const int xcd = id & 7, r8 = id >> 3;   // r8: 0..95
  const int xo = r8 & 3, yz = r8 >> 2;    // yz: 0..23
  const int y = yz & 7, z = yz >> 3;      // y: 0..7, z: 0..2
  const int mBase = (xcd * 4 + xo) * 128, nBase = y * 128;

  const u16* Bt = (z == 0) ? Wq : (z == 1) ? Wk : Wv;
  u16* D = (z == 0) ? Qo : (z == 1) ? Ko : Vo;
  const float scale = (z == 0) ? QSCALE : 1.0f;

  f32x4 acc[4][4];
#pragma unroll
  for (int mi = 0; mi < 4; mi++)
#pragma unroll
    for (int ni = 0; ni < 4; ni++) acc[mi][ni] = (f32x4)0.0f;

  auto stage = [&](int buf, int k0) {
#pragma unroll
    for (int i = 0; i < 2; i++) {
      int c = i * 256 + tid;
      int r = c >> 2, kk = (c & 3) << 3;
      gld16(&X[(size_t)(mBase + r) * 1024 + k0 + kk], &sm[buf * 4096 + c * 8]);
      gld16(&Bt[(size_t)(nBase + r) * 1024 + k0 + kk],
            &sm[8192 + buf * 4096 + c * 8]);
    }
  };

  stage(0, 0);
  __syncthreads();
  int cur = 0;
  for (int k0 = 0; k0 < 1024; k0 += 32) {
    if (k0 + 32 < 1024) stage(cur ^ 1, k0 + 32);
    short8 af[4], bf[4];
#pragma unroll
    for (int mi = 0; mi < 4; mi++)
      af[mi] = *(const short8*)&sm[cur * 4096 + (wm + mi * 16 + lrow) * 32 + lk];
#pragma unroll
    for (int ni = 0; ni < 4; ni++)
      bf[ni] =
          *(const short8*)&sm[8192 + cur * 4096 + (wn + ni * 16 + lrow) * 32 + lk];
#pragma unroll
    for (int mi = 0; mi < 4; mi++)
#pragma unroll
      for (int ni = 0; ni < 4; ni++)
        acc[mi][ni] = MFMA_BF16(af[mi], bf[ni], acc[mi][ni]);
    __syncthreads();  // drains vmcnt (next tile landed) + lgkm
    cur ^= 1;
  }

  if (z != 2) {
#pragma unroll
    for (int mi = 0; mi < 4; mi++)
#pragma unroll
      for (int r = 0; r < 4; r++) {
        int m = mBase + wm + mi * 16 + lq + r;
        int b = m >> 11, t = m & 2047;
#pragma unroll
        for (int ni = 0; ni < 4; ni++) {
          int n = nBase + wn + ni * 16 + lrow;
          int h = n >> 6, dd = n & 63;
          D[(((size_t)(b * NHEADS + h)) * T_SEQ + t) * DHEAD + dd] =
              f2bf(acc[mi][ni][r] * scale);
        }
      }
  } else {
    // V: per-wave 64x64 transpose in LDS (granule-XOR swizzle), then
    // coalesced stores: 8 lanes x 16B = 128B contiguous along t per d-row.
    u16* TT = &sm[w * 4096];  // wave-private -> no barrier needed
#pragma unroll
    for (int mi = 0; mi < 4; mi++)
#pragma unroll
      for (int r = 0; r < 4; r++) {
        int t_loc = mi * 16 + lq + r;
#pragma unroll
        for (int ni = 0; ni < 4; ni++) {
          int d_loc = ni * 16 + lrow;
          TT[d_loc * 64 + ((((t_loc >> 3) ^ (d_loc & 7)) << 3) | (t_loc & 7))] =
              f2bf(acc[mi][ni][r]);
        }
      }
    const int b = (mBase + wm) >> 11;
    const int t0 = (mBase + wm) & 2047;
#pragma unroll
    for (int it = 0; it < 8; it++) {
      int d_loc = it * 8 + (lane >> 3);
      int ch = lane & 7;
      short8 v = *(const short8*)&TT[d_loc * 64 + ((ch ^ (d_loc & 7)) << 3)];
      int n = nBase + wn + d_loc;
      int h = n >> 6, dd = n & 63;
      *(uint4v*)&D[(((size_t)((b * NHEADS + h) * DHEAD + dd)) * T_SEQ) + t0 +
                   ch * 8] = *(const uint4v*)&v;
    }
  }
}

// ---------------------------------------------------------------- attention
// 32x32-MFMA rewrite: R7 proved the DS pipe is the binding resource (~60% of
// walltime). mfma_f32_32x32x16_bf16 halves LDS reads per FLOP (1 b128 A-read
// per MFMA) and the P matrix never touches LDS: S->B-frag redistribution is
// done in-register with 4 packs + 4 shfl_xor(32) + 4 selects per k-step
// (exact: frag j<4 sources half-0 regs 4*(2ks'+h_c)+j, j>=4 half-1).
// Block = 512 thr = 2 kv-parity groups x 4 waves; q-tile 128 (wave owns 32
// q-cols, lane&31 = q; lane>>5 = kv/d half). kv tile count per block is even
// -> both groups always active; exact flash-merge at the end via freed LDS.
// LDS = K 4-slot + V 4-slot = 64KB -> 2 blocks/CU. Layouts used:
//   C/D: col=lane&31, row=(reg&3)+8*(reg>>2)+4*(lane>>5)   [m74/m101]
//   A/B: row|col=lane&31, k=(lane>>5)*8+{0..7} per 16-k step
// Decode: id&7 = XCD (4 bh each, proven FETCH 123->12.4MB); qt pairs
// (id, id+256) sum to 15 for per-CU balance.
__global__ __launch_bounds__(512, 4) void attn_qt32(
    const u16* __restrict__ Qg, const u16* __restrict__ Kg,
    const u16* __restrict__ Vtg, u16* __restrict__ Ob) {
  __shared__ __attribute__((aligned(16))) u16 smem[32768];  // 65536 B

  const int tid = threadIdx.x;
  const int w = tid >> 6, lane = tid & 63;
  const int g = w >> 2;             // kv-parity group 0/1
  const int wg = w & 3;             // wave's 32-q slice within the 128-q tile
  const int l31 = lane & 31, h = lane >> 5;
  const int rsw = l31 & 7;          // read-side swizzle key (= row&7)

  const int id = blockIdx.x;        // 0..511
  const int half = id >> 8;
  const int x = id & 255;
  const int xcd = x & 7;
  const int u = x >> 3;             // 0..31
  const int bh = xcd * 4 + (u & 3);
  const int qp = u >> 2;            // 0..7
  const int qt = half ? (15 - qp) : qp;  // co-resident pair sums to 15
  const int b = bh >> 4, hh = bh & 15;
  const int qb = qt << 7;
  const u16* Qp = Qg + (size_t)bh * T_SEQ * DHEAD;
  const u16* Kp = Kg + (size_t)bh * T_SEQ * DHEAD;
  const u16* Vp = Vtg + (size_t)bh * DHEAD * T_SEQ;
  const int lastT = 2 * qt + 1;

  // stage one 64x64 tile of K and V^T into slot T&3 (512 thr x 16B = 8KB each)
  auto stage_tile = [&](int T) {
    if (T > lastT) return;
    const int slot = T & 3;
    const int r = tid >> 3;
    const int sw = ((tid & 7) ^ (r & 7)) << 3;  // pre-swizzled global granule
    gld16(&Kp[(size_t)(T * 64 + r) * DHEAD + sw], &smem[slot * 4096 + tid * 8]);
    gld16(&Vp[(size_t)r * T_SEQ + T * 64 + sw],
          &smem[16384 + slot * 4096 + tid * 8]);
  };

  stage_tile(0);
  stage_tile(1);

  const int qg = qb + wg * 32 + l31;  // this lane's global q row
  short8 qf[4];                        // Q B-frags: k = ks*16 + h*8 + {0..7}
#pragma unroll
  for (int ks = 0; ks < 4; ks++)
    qf[ks] = *(const short8*)&Qp[(size_t)qg * DHEAD + ks * 16 + h * 8];

  float mst = NEG_BIG, lst = 0.f;
  f32x16 oa0 = (f32x16)0.f, oa1 = (f32x16)0.f;  // O^T d-tiles 0/1 (col=q)
  __syncthreads();  // tile 0/1 DMA drained

  for (int s = 0; s <= qt; s++) {
    stage_tile(2 * s + 2);  // prefetch next pair (slots free: read 2 iters ago)
    stage_tile(2 * s + 3);
    const int T = 2 * s + g;
    const u16* Kc = &smem[(T & 3) * 4096];
    const u16* Vc = &smem[16384 + (T & 3) * 4096];

#pragma unroll
    for (int kvt2 = 0; kvt2 < 2; kvt2++) {  // 32-kv half-tiles
      f32x16 S = (f32x16)0.f;
      __builtin_amdgcn_s_setprio(1);
#pragma unroll
      for (int ks = 0; ks < 4; ks++) {
        short8 kf = *(const short8*)&Kc[(kvt2 * 32 + l31) * 64 +
                                        (((ks * 2 + h) ^ rsw) << 3)];
        S = MFMA32(kf, qf[ks], S);
      }
      __builtin_amdgcn_s_setprio(0);

      if (s == qt) {  // causal mask (only final super-iter can touch diagonal)
        const int kvb2 = T * 64 + kvt2 * 32 + 4 * h;
#pragma unroll
        for (int r = 0; r < 16; r++) {
          int kv = kvb2 + (r & 3) + 8 * (r >> 2);
          if (kv > qg) S[r] = NEG_BIG;
        }
      }

      // online softmax over this 32-kv half (per-lane; halves merged by shfl32)
      float mx = NEG_BIG;
#pragma unroll
      for (int r = 0; r < 16; r += 4)
        mx = fmaxf(mx, fmaxf(fmaxf(S[r], S[r + 1]), fmaxf(S[r + 2], S[r + 3])));
      mx = fmaxf(mx, __shfl_xor(mx, 32));
      if (!__all(mx <= mst + RESCALE_THR)) {  // T13 defer-max
        float mn = fmaxf(mst, mx);
        float corr = EXP2(mst - mn);
        mst = mn;
        lst *= corr;
#pragma unroll
        for (int r = 0; r < 16; r++) {
          oa0[r] *= corr;
          oa1[r] *= corr;
        }
      }
      float ls = 0.f;
#pragma unroll
      for (int r = 0; r < 16; r++) {
        float pv = EXP2(S[r] - mst);
        S[r] = pv;
        ls += pv;
      }
      ls += __shfl_xor(ls, 32);
      lst += ls;

      // P -> B-frags in-register (no LDS) + PV, per 16-kv k-step
#pragma unroll
      for (int ks2 = 0; ks2 < 2; ks2++) {
        unsigned P0 = pk2(S[8 * ks2 + 0], S[8 * ks2 + 1]);
        unsigned P1 = pk2(S[8 * ks2 + 2], S[8 * ks2 + 3]);
        unsigned P2 = pk2(S[8 * ks2 + 4], S[8 * ks2 + 5]);
        unsigned P3 = pk2(S[8 * ks2 + 6], S[8 * ks2 + 7]);
        unsigned R0 = __shfl_xor(P0, 32), R1 = __shfl_xor(P1, 32);
        unsigned R2 = __shfl_xor(P2, 32), R3 = __shfl_xor(P3, 32);
        uint4v fu;
        fu[0] = h ? R2 : P0;  // k j=0,1 (always sourced from half 0)
        fu[1] = h ? R3 : P1;  // k j=2,3
        fu[2] = h ? P2 : R0;  // k j=4,5 (always sourced from half 1)
        fu[3] = h ? P3 : R1;  // k j=6,7
        short8 pf = *(short8*)&fu;
        const int kgr = kvt2 * 4 + ks2 * 2 + h;  // V kv-granule of this k-step
        __builtin_amdgcn_s_setprio(1);
        short8 vf0 = *(const short8*)&Vc[l31 * 64 + ((kgr ^ rsw) << 3)];
        oa0 = MFMA32(vf0, pf, oa0);
        short8 vf1 = *(const short8*)&Vc[(32 + l31) * 64 + ((kgr ^ rsw) << 3)];
        oa1 = MFMA32(vf1, pf, oa1);
        __builtin_amdgcn_s_setprio(0);
      }
    }
    __syncthreads();  // next pair's DMA drained; this pair's readers done
  }

  // merge: group 1 publishes (O^T, m, l) into freed K/V LDS; group 0 combines.
  float* O1 = (float*)smem;          // [128 q][64 d] f32, granule-swizzled
  float* ml = (float*)&smem[16384];  // m[128], l[128]
  const int q = wg * 32 + l31;
  if (g == 1) {
#pragma unroll
    for (int dt = 0; dt < 2; dt++)
#pragma unroll
      for (int t4 = 0; t4 < 4; t4++) {
        int gr = dt * 8 + t4 * 2 + h;  // 16B granule index within the q-row
        int swg = (gr & 8) | ((gr & 7) ^ (q & 7));
        f32x4 v;
#pragma unroll
        for (int j = 0; j < 4; j++) v[j] = dt ? oa1[t4 * 4 + j] : oa0[t4 * 4 + j];
        *(f32x4*)&O1[q * 64 + swg * 4] = v;
      }
    if (h == 0) {
      ml[q] = mst;
      ml[128 + q] = lst;
    }
  }
  __syncthreads();
  if (g == 0) {
    const float m1 = ml[q], l1 = ml[128 + q];
    const float M = fmaxf(mst, m1);
    const float c0 = EXP2(mst - M), c1 = EXP2(m1 - M);
    const float inv = 1.f / (c0 * lst + c1 * l1);
    size_t rowbase = ((size_t)(b * T_SEQ + qb + q)) * DMODEL + hh * DHEAD;
#pragma unroll
    for (int dt = 0; dt < 2; dt++)
#pragma unroll
      for (int t4 = 0; t4 < 4; t4++) {
        int gr = dt * 8 + t4 * 2 + h;
        int swg = (gr & 8) | ((gr & 7) ^ (q & 7));
        f32x4 o1 = *(const f32x4*)&O1[q * 64 + swg * 4];
        float a0 = (c0 * (dt ? oa1[t4 * 4 + 0] : oa0[t4 * 4 + 0]) + c1 * o1[0]) * inv;
        float a1 = (c0 * (dt ? oa1[t4 * 4 + 1] : oa0[t4 * 4 + 1]) + c1 * o1[1]) * inv;
        float a2 = (c0 * (dt ? oa1[t4 * 4 + 2] : oa0[t4 * 4 + 2]) + c1 * o1[2]) * inv;
        float a3 = (c0 * (dt ? oa1[t4 * 4 + 3] : oa0[t4 * 4 + 3]) + c1 * o1[3]) * inv;
        uint2v pk;
        pk[0] = (unsigned)f2bf(a0) | ((unsigned)f2bf(a1) << 16);
        pk[1] = (unsigned)f2bf(a2) | ((unsigned)f2bf(a3) << 16);
        *(uint2v*)&Ob[rowbase + dt * 32 + t4 * 8 + 4 * h] = pk;
      }
  }
}

// ---------------------------------------------------------------- out proj (bf16)
// 1-D grid 512, XCD-swizzled. BN=64 -> 2 blocks/CU.
__global__ __launch_bounds__(256) void gemm_out_bf(const u16* __restrict__ O,
                                                   const u16* __restrict__ Wo,
                                                   float* __restrict__ Out) {
  __shared__ __attribute__((aligned(16))) u16 As[2][128 * 32];
  __shared__ __attribute__((aligned(16))) u16 Bs[2][64 * 32];
  const int tid = threadIdx.x, lane = tid & 63, w = tid >> 6;
  const int wm = (w >> 1) * 64, wn = (w & 1) * 32;
  const int lrow = lane & 15;
  const int lk = (lane >> 4) << 3;
  const int lq = (lane >> 4) << 2;

  const int id = blockIdx.x;            // 0..511
  const int xcd = id & 7, r8 = id >> 3; // 0..63
  const int xo = r8 & 3, y = r8 >> 2;   // y: 0..15
  const int mBase = (xcd * 4 + xo) * 128, nBase = y * 64;

  f32x4 acc[4][2];
#pragma unroll
  for (int mi = 0; mi < 4; mi++)
#pragma unroll
    for (int ni = 0; ni < 2; ni++) acc[mi][ni] = (f32x4)0.0f;

  auto stage = [&](int buf, int k0) {
#pragma unroll
    for (int i = 0; i < 2; i++) {
      int c = i * 256 + tid;
      int r = c >> 2, kk = (c & 3) << 3;
      gld16(&O[(size_t)(mBase + r) * 1024 + k0 + kk], &As[buf][c * 8]);
    }
    int r = tid >> 2, kk = (tid & 3) << 3;
    gld16(&Wo[(size_t)(nBase + r) * 1024 + k0 + kk], &Bs[buf][tid * 8]);
  };

  stage(0, 0);
  __syncthreads();
  int cur = 0;
  for (int k0 = 0; k0 < 1024; k0 += 32) {
    if (k0 + 32 < 1024) stage(cur ^ 1, k0 + 32);
    short8 af[4], bf[2];
#pragma unroll
    for (int mi = 0; mi < 4; mi++)
      af[mi] = *(const short8*)&As[cur][(wm + mi * 16 + lrow) * 32 + lk];
#pragma unroll
    for (int ni = 0; ni < 2; ni++)
      bf[ni] = *(const short8*)&Bs[cur][(wn + ni * 16 + lrow) * 32 + lk];
#pragma unroll
    for (int mi = 0; mi < 4; mi++)
#pragma unroll
      for (int ni = 0; ni < 2; ni++)
        acc[mi][ni] = MFMA_BF16(af[mi], bf[ni], acc[mi][ni]);
    __syncthreads();
    cur ^= 1;
  }
#pragma unroll
  for (int mi = 0; mi < 4; mi++)
#pragma unroll
    for (int r = 0; r < 4; r++) {
      int m = mBase + wm + mi * 16 + lq + r;
#pragma unroll
      for (int ni = 0; ni < 2; ni++)
        Out[(size_t)m * DMODEL + nBase + wn + ni * 16 + lrow] = acc[mi][ni][r];
    }
}

// ---------------------------------------------------------------- launch
extern "C" void kernel_launch(void* const* d_in, const int* in_sizes, int n_in,
                              void* d_out, int out_size, void* d_ws,
                              size_t ws_size, hipStream_t stream) {
  const float* x = (const float*)d_in[0];
  const float* Wq = (const float*)d_in[1];
  const float* Wk = (const float*)d_in[2];
  const float* Wv = (const float*)d_in[3];
  const float* Wo = (const float*)d_in[4];
  float* out = (float*)d_out;

  u16* xh = (u16*)d_ws;      // 4M elems
  u16* wqh = xh + 4194304;   // 1M each
  u16* wkh = wqh + 1048576;
  u16* wvh = wkh + 1048576;
  u16* woh = wvh + 1048576;
  u16* Q = woh + 1048576;    // 4M each; V stored transposed (b,h,d,t)
  u16* K = Q + 4194304;
  u16* V = K + 4194304;
  u16* O = V + 4194304;      // total 48 MB

  cvt_all<<<dim3(4096), 256, 0, stream>>>(x, Wq, Wk, Wv, Wo, xh, wqh, wkh, wvh, woh);
  gemm_qkv<<<dim3(768), 256, 0, stream>>>(xh, wqh, wkh, wvh, Q, K, V);
  attn_qt32<<<dim3(512), 512, 0, stream>>>(Q, K, V, O);
  gemm_out_bf<<<dim3(512), 256, 0, stream>>>(O, woh, out);
}